// Round 21
// baseline (228.166 us; speedup 1.0000x reference)
//
#include <hip/hip_runtime.h>

// EntityClassify (R-GCN) — round 21: final pull-side concurrency push.
// r20 post-mortem: per-wave hist NULL -> bin contention immaterial; fused1
// (100us) closed after 6 falsified theories. Remaining lever: pull1 gather
// holds only 2 independent loads/lane. This round: (a) pull1 4-node
// interleaved gather (4 acc sets, +33% outstanding loads/CU despite VGPR
// cliff 24->16 waves); (b) pull2 2-node interleave. All else r20 verbatim.

constexpr int NN = 100000, RR = 4, EE = 800000;
constexpr int RE = RR * EE;
constexpr int NBKT = (NN + 63) / 64;      // 1563 fine buckets (64 dst nodes)
constexpr int BCAP = 3072;                // fine-bucket capacity (λ≈2046)
constexpr int NCOARSE = 49;               // dst>>11
constexpr int CCAP = 69632;               // 17*4096
constexpr int NCH = 17;
constexpr int NG1 = (NN + 63) / 64;       // 1563 gemm1 tiles (M=64)
constexpr int CHUNK = 4096;
constexpr int NB = (RE + CHUNK - 1) / CHUNK;  // 782 bin blocks
constexpr int EPT = CHUNK / 512;          // 8 edges per thread

typedef short bf16x8 __attribute__((ext_vector_type(8)));
typedef float f32x4 __attribute__((ext_vector_type(4)));

__device__ inline unsigned short f2bf(float f) {
  unsigned u = __float_as_uint(f);
  u += 0x7FFF + ((u >> 16) & 1);
  return (unsigned short)(u >> 16);
}
__device__ inline float bf2f(unsigned short s) {
  return __uint_as_float(((unsigned)s) << 16);
}

// ---- weights -> bf16 [n][k]: BT1 [320][256], BT2 [80][64] ----
__global__ __launch_bounds__(256) void prep_w_kernel(const float* __restrict__ W1,
                                                     const float* __restrict__ L1w,
                                                     const float* __restrict__ W2,
                                                     const float* __restrict__ L2w,
                                                     unsigned short* __restrict__ BT1,
                                                     unsigned short* __restrict__ BT2) {
  int idx = blockIdx.x * 256 + threadIdx.x;
  if (idx < 320 * 256) {
    int n = idx >> 8, k = idx & 255;
    float v = (n < 256) ? W1[((size_t)((n >> 6) * 256 + k)) * 64 + (n & 63)]
                        : L1w[(size_t)k * 64 + (n - 256)];
    BT1[idx] = f2bf(v);
  } else {
    int j = idx - 320 * 256;
    if (j < 80 * 64) {
      int n = j >> 6, k = j & 63;
      float v = (n < 64) ? W2[((size_t)((n >> 4) * 64 + k)) * 16 + (n & 15)]
                         : L2w[(size_t)k * 16 + (n - 64)];
      BT2[j] = f2bf(v);
    }
  }
}

// ---- fused1 (r20): coarse-bin blocks (every 3rd) ∥ gemm1 blocks ----
__global__ __launch_bounds__(512) void fused1_kernel(const float* __restrict__ x,
                                                     const unsigned short* __restrict__ BT1,
                                                     const float* __restrict__ L1b,
                                                     const int* __restrict__ src,
                                                     const int* __restrict__ dst,
                                                     int* __restrict__ gcoarse,
                                                     int* __restrict__ cbuf,
                                                     unsigned short* __restrict__ hwcat,
                                                     unsigned short* __restrict__ h) {
  __shared__ char lds[49152];
  const int bid = blockIdx.x;
  const int t = threadIdx.x;
  const bool is_bin = (bid % 3 == 0) && (bid / 3 < NB);

  if (is_bin) {
    int* whist = (int*)lds;                     // [8][64]
    int* base  = (int*)(lds + 2048);            // [64]
    int* delta = (int*)(lds + 2304);            // [64]
    int* wbase = (int*)(lds + 2560);            // [8][64]
    int* sorted = (int*)(lds + 4608);           // [4096]
    unsigned char* cb = (unsigned char*)(lds + 20992);
    const int fid = bid / 3;
    const int wid = t >> 6;

    whist[t] = 0;
    __syncthreads();
    const int e0 = fid * CHUNK + t;
    int dl[EPT], sl[EPT];
#pragma unroll
    for (int i = 0; i < EPT; ++i) {
      int fl = e0 + i * 512;
      dl[i] = -1;
      if (fl < RE) {
        dl[i] = dst[fl];
        sl[i] = src[fl];
        atomicAdd(&whist[wid * 64 + (dl[i] >> 11)], 1);
      }
    }
    __syncthreads();
    if (t < 64) {
      int run = 0;
#pragma unroll
      for (int w = 0; w < 8; ++w) {
        wbase[w * 64 + t] = run;
        run += whist[w * 64 + t];
      }
      int xs = run;
#pragma unroll
      for (int d = 1; d < 64; d <<= 1) {
        int y = __shfl_up(xs, d);
        if (t >= d) xs += y;
      }
      int excl = xs - run;
      base[t] = excl;
      int gb = (run > 0) ? atomicAdd(&gcoarse[t], run) : 0;
      delta[t] = gb - excl;
    }
    __syncthreads();
    whist[t] = 0;
    __syncthreads();
#pragma unroll
    for (int i = 0; i < EPT; ++i) {
      if (dl[i] < 0) continue;
      int fl = e0 + i * 512;
      int r = fl / EE;
      int cg = dl[i] >> 11;
      int p = base[cg] + wbase[wid * 64 + cg] + atomicAdd(&whist[wid * 64 + cg], 1);
      sorted[p] = (sl[i] << 2) | r | ((dl[i] & 2047) << 19);
      cb[p] = (unsigned char)cg;
    }
    __syncthreads();
    int ptot = RE - fid * CHUNK;
    if (ptot > CHUNK) ptot = CHUNK;
#pragma unroll
    for (int i = 0; i < EPT; ++i) {
      int p = t + i * 512;
      if (p < ptot) {
        int cg = cb[p];
        int inb = delta[cg] + p;
        if (inb < CCAP) cbuf[(size_t)cg * CCAP + inb] = sorted[p];
      }
    }
    return;
  }

  // ---- gemm1 role (r13): M-tile 64, N=320, K=256, BK=64 ----
  int nbins = (bid + 2) / 3;
  if (nbins > NB) nbins = NB;
  const int m0 = (bid - nbins) * 64;
  char* Al = lds;
  char* Bl = lds + 8192;
  const int wid = t >> 6, lane = t & 63;
  const int wm = wid >> 2, wn = wid & 3;
  const int l15 = lane & 15, g = lane >> 4;

  f32x4 acc[2][5];
#pragma unroll
  for (int i = 0; i < 2; ++i)
#pragma unroll
    for (int j = 0; j < 5; ++j) acc[i][j] = (f32x4){0.f, 0.f, 0.f, 0.f};

  for (int kc = 0; kc < 4; ++kc) {
    if (kc) __syncthreads();
#pragma unroll
    for (int it = 0; it < 2; ++it) {
      int fl = t + 512 * it;
      int row = fl >> 4, kq = (fl & 15) * 4;
      int rg = m0 + row;
      float4 v = (rg < NN) ? *(const float4*)(x + (size_t)rg * 256 + kc * 64 + kq)
                           : make_float4(0.f, 0.f, 0.f, 0.f);
      ushort4 pck = {f2bf(v.x), f2bf(v.y), f2bf(v.z), f2bf(v.w)};
      int wb = ((row * 64 + kq) * 2) ^ ((row & 7) << 4);
      *(ushort4*)(Al + wb) = pck;
    }
#pragma unroll
    for (int it = 0; it < 5; ++it) {
      int fl = t + 512 * it;
      int n = fl >> 3, i8 = (fl & 7) * 8;
      uint4 u = *(const uint4*)(BT1 + (size_t)n * 256 + kc * 64 + i8);
      int wb = ((n * 64 + i8) * 2) ^ ((n & 7) << 4);
      *(uint4*)(Bl + wb) = u;
    }
    __syncthreads();
#pragma unroll
    for (int ks = 0; ks < 2; ++ks) {
      bf16x8 af[2], bfr[5];
#pragma unroll
      for (int mi = 0; mi < 2; ++mi) {
        int row = wm * 32 + mi * 16 + l15;
        int byte = ((row * 64 + ks * 32 + g * 8) * 2) ^ ((row & 7) << 4);
        af[mi] = *(const bf16x8*)(Al + byte);
      }
#pragma unroll
      for (int ni = 0; ni < 5; ++ni) {
        int n = wn * 80 + ni * 16 + l15;
        int byte = ((n * 64 + ks * 32 + g * 8) * 2) ^ ((n & 7) << 4);
        bfr[ni] = *(const bf16x8*)(Bl + byte);
      }
#pragma unroll
      for (int mi = 0; mi < 2; ++mi)
#pragma unroll
        for (int ni = 0; ni < 5; ++ni)
          acc[mi][ni] = __builtin_amdgcn_mfma_f32_16x16x32_bf16(af[mi], bfr[ni], acc[mi][ni], 0, 0, 0);
    }
  }
#pragma unroll
  for (int mi = 0; mi < 2; ++mi) {
    int rbase = m0 + wm * 32 + mi * 16 + 4 * g;
#pragma unroll
    for (int ni = 0; ni < 5; ++ni) {
      int n0 = wn * 80 + ni * 16;
      int n = n0 + l15;
#pragma unroll
      for (int e = 0; e < 4; ++e) {
        int row = rbase + e;
        if (row >= NN) continue;
        float v = acc[mi][ni][e];
        if (n0 < 256) hwcat[(size_t)row * 256 + n] = f2bf(v);
        else h[(size_t)row * 64 + (n - 256)] = f2bf(v + L1b[n - 256]);
      }
    }
  }
}

// ---- pass 2 (r18): coarse chunk -> 32 fine buckets ----
__global__ __launch_bounds__(512) void pass2_kernel(const int* __restrict__ cbuf,
                                                    const int* __restrict__ gcoarse,
                                                    int* __restrict__ gcur,
                                                    int* __restrict__ binned) {
  __shared__ int hist32[32], cur32[32], delta32[32];
  __shared__ int sorted[4096];
  __shared__ unsigned char cb[4096];
  const int t = threadIdx.x;
  const int g = blockIdx.x / NCH, ch = blockIdx.x % NCH;
  int count = gcoarse[g];
  if (count > CCAP) count = CCAP;
  const int base = ch * 4096;
  int nhere = count - base;
  if (nhere <= 0) return;
  if (nhere > 4096) nhere = 4096;

  if (t < 32) hist32[t] = 0;
  __syncthreads();
  int wl[8], fl8[8];
#pragma unroll
  for (int i = 0; i < 8; ++i) {
    int j = t + i * 512;
    fl8[i] = -1;
    if (j < nhere) {
      int w = cbuf[(size_t)g * CCAP + base + j];
      wl[i] = w;
      fl8[i] = (w >> 25) & 31;
      atomicAdd(&hist32[fl8[i]], 1);
    }
  }
  __syncthreads();
  if (t < 32) {
    int c = hist32[t];
    int xs = c;
#pragma unroll
    for (int d = 1; d < 32; d <<= 1) {
      int y = __shfl_up(xs, d);
      if (t >= d) xs += y;
    }
    int excl = xs - c;
    cur32[t] = excl;
    int gb = (c > 0) ? atomicAdd(&gcur[g * 32 + t], c) : 0;
    delta32[t] = gb - excl;
  }
  __syncthreads();
#pragma unroll
  for (int i = 0; i < 8; ++i) {
    if (fl8[i] < 0) continue;
    int p = atomicAdd(&cur32[fl8[i]], 1);
    int w = wl[i];
    sorted[p] = (w & 0x7FFFF) | (((w >> 19) & 63) << 19);
    cb[p] = (unsigned char)fl8[i];
  }
  __syncthreads();
#pragma unroll
  for (int i = 0; i < 8; ++i) {
    int p = t + i * 512;
    if (p < nhere) {
      int f = cb[p];
      int inb = delta32[f] + p;
      if (inb < BCAP) binned[(size_t)(g * 32 + f) * BCAP + inb] = sorted[p];
    }
  }
}

// ---- pull-L1 + gemm2: 4-node-interleaved gather ----
__global__ __launch_bounds__(256) void pull1_kernel(const unsigned short* __restrict__ h,
                                                    const unsigned short* __restrict__ hwcat,
                                                    int* __restrict__ binned,
                                                    const int* __restrict__ gcur,
                                                    const unsigned short* __restrict__ BT2,
                                                    const float* __restrict__ L2b,
                                                    unsigned* __restrict__ hdrG,
                                                    float* __restrict__ winvG,
                                                    unsigned short* __restrict__ hw2,
                                                    float* __restrict__ out) {
  __shared__ int csr[BCAP];
  __shared__ int cnt[256];
  __shared__ int off[256];
  __shared__ float winv[256];
  __shared__ int tot[64];
  __shared__ int wsum[4];
  __shared__ char Al[64 * 64 * 2];
  const int t = threadIdx.x, bkt = blockIdx.x;
  const int wid = t >> 6, lane = t & 63;
  const int l15 = lane & 15, g = lane >> 4;

  int count = gcur[bkt];
  if (count > BCAP) count = BCAP;
  const int* edges = binned + (size_t)bkt * BCAP;

  cnt[t] = 0;
  __syncthreads();
  for (int i = t; i < count; i += 256) {
    int w = edges[i];
    atomicAdd(&cnt[((w >> 19) & 63) * 4 + (w & 3)], 1);
  }
  __syncthreads();
  int v = cnt[t];
  int xs = v;
#pragma unroll
  for (int d = 1; d < 64; d <<= 1) {
    int y = __shfl_up(xs, d);
    if (lane >= d) xs += y;
  }
  if (lane == 63) wsum[wid] = xs;
  __syncthreads();
  int add = 0;
#pragma unroll
  for (int w2 = 0; w2 < 4; ++w2)
    if (w2 < wid) add += wsum[w2];
  int excl = xs + add - v;
  winv[t] = 1.0f / (float)(v > 1 ? v : 1);
  off[t] = excl;
  cnt[t] = excl;
  __syncthreads();
  if (t < 64) tot[t] = ((t == 63) ? count : off[(t + 1) * 4]) - off[t * 4];
  for (int i = t; i < count; i += 256) {
    int w = edges[i];
    int k = ((w >> 19) & 63) * 4 + (w & 3);
    int p = atomicAdd(&cnt[k], 1);
    csr[p] = w & 0x7FFFF;
  }
  __syncthreads();

  // handoff: built CSR + headers + winv -> global (pull2 skips build)
  for (int i = t; i < count; i += 256) binned[(size_t)bkt * BCAP + i] = csr[i];
  winvG[bkt * 256 + t] = winv[t];
  if (t < 64) hdrG[bkt * 64 + t] = (unsigned)off[t * 4] | ((unsigned)tot[t] << 16);

  // gather: 4 nodes concurrently per wave; 8 slots x 16B each
  const int slot = lane >> 3, cpart = lane & 7;
  for (int ii = 0; ii < 16; ii += 4) {
    int nA = wid * 16 + ii, nB = nA + 1, nC = nA + 2, nD = nA + 3;
    int begA = off[nA * 4], totA = tot[nA];
    int begB = off[nB * 4], totB = tot[nB];
    int begC = off[nC * 4], totC = tot[nC];
    int begD = off[nD * 4], totD = tot[nD];
    int tmax = totA > totB ? totA : totB;
    tmax = tmax > totC ? tmax : totC;
    tmax = tmax > totD ? tmax : totD;
    float accA[8] = {0.f, 0.f, 0.f, 0.f, 0.f, 0.f, 0.f, 0.f};
    float accB[8] = {0.f, 0.f, 0.f, 0.f, 0.f, 0.f, 0.f, 0.f};
    float accC[8] = {0.f, 0.f, 0.f, 0.f, 0.f, 0.f, 0.f, 0.f};
    float accD[8] = {0.f, 0.f, 0.f, 0.f, 0.f, 0.f, 0.f, 0.f};
    for (int p0 = 0; p0 < tmax; p0 += 8) {
      int j = p0 + slot;
      bool prA = j < totA, prB = j < totB, prC = j < totC, prD = j < totD;
      int keyA = prA ? csr[begA + j] : 0;
      int keyB = prB ? csr[begB + j] : 0;
      int keyC = prC ? csr[begC + j] : 0;
      int keyD = prD ? csr[begD + j] : 0;
      float wvA = prA ? winv[nA * 4 + (keyA & 3)] : 0.f;
      float wvB = prB ? winv[nB * 4 + (keyB & 3)] : 0.f;
      float wvC = prC ? winv[nC * 4 + (keyC & 3)] : 0.f;
      float wvD = prD ? winv[nD * 4 + (keyD & 3)] : 0.f;
      uint4 uA = *(const uint4*)(hwcat + (size_t)keyA * 64 + cpart * 8);
      uint4 uB = *(const uint4*)(hwcat + (size_t)keyB * 64 + cpart * 8);
      uint4 uC = *(const uint4*)(hwcat + (size_t)keyC * 64 + cpart * 8);
      uint4 uD = *(const uint4*)(hwcat + (size_t)keyD * 64 + cpart * 8);
#pragma unroll
      for (int q = 0; q < 4; ++q) {
        unsigned a = (&uA.x)[q], b = (&uB.x)[q], c = (&uC.x)[q], d = (&uD.x)[q];
        accA[q * 2]     = fmaf(wvA, bf2f((unsigned short)(a & 0xffffu)), accA[q * 2]);
        accA[q * 2 + 1] = fmaf(wvA, bf2f((unsigned short)(a >> 16)), accA[q * 2 + 1]);
        accB[q * 2]     = fmaf(wvB, bf2f((unsigned short)(b & 0xffffu)), accB[q * 2]);
        accB[q * 2 + 1] = fmaf(wvB, bf2f((unsigned short)(b >> 16)), accB[q * 2 + 1]);
        accC[q * 2]     = fmaf(wvC, bf2f((unsigned short)(c & 0xffffu)), accC[q * 2]);
        accC[q * 2 + 1] = fmaf(wvC, bf2f((unsigned short)(c >> 16)), accC[q * 2 + 1]);
        accD[q * 2]     = fmaf(wvD, bf2f((unsigned short)(d & 0xffffu)), accD[q * 2]);
        accD[q * 2 + 1] = fmaf(wvD, bf2f((unsigned short)(d >> 16)), accD[q * 2 + 1]);
      }
    }
#pragma unroll
    for (int m = 8; m <= 32; m <<= 1)
#pragma unroll
      for (int q = 0; q < 8; ++q) {
        accA[q] += __shfl_xor(accA[q], m);
        accB[q] += __shfl_xor(accB[q], m);
        accC[q] += __shfl_xor(accC[q], m);
        accD[q] += __shfl_xor(accD[q], m);
      }
    if (slot == 0) {
#pragma unroll
      for (int s2 = 0; s2 < 4; ++s2) {
        int nloc = wid * 16 + ii + s2;
        const float* ac = (s2 == 0) ? accA : (s2 == 1) ? accB : (s2 == 2) ? accC : accD;
        int gn = bkt * 64 + nloc;
        unsigned pk[4];
        uint4 hu = make_uint4(0, 0, 0, 0);
        if (gn < NN) hu = *(const uint4*)(h + (size_t)gn * 64 + cpart * 8);
#pragma unroll
        for (int q = 0; q < 4; ++q) {
          unsigned a = (&hu.x)[q];
          float v0 = ac[q * 2]     + bf2f((unsigned short)(a & 0xffffu));
          float v1 = ac[q * 2 + 1] + bf2f((unsigned short)(a >> 16));
          pk[q] = (unsigned)f2bf(fmaxf(v0, 0.f)) | ((unsigned)f2bf(fmaxf(v1, 0.f)) << 16);
        }
        int wb = ((nloc * 64 + cpart * 8) * 2) ^ ((nloc & 7) << 4);
        *(uint4*)(Al + wb) = make_uint4(pk[0], pk[1], pk[2], pk[3]);
      }
    }
  }
  __syncthreads();

  char* Bl = (char*)csr;
#pragma unroll
  for (int it = 0; it < 3; ++it) {
    int fl = t + 256 * it;
    if (fl < 640) {
      int n = fl >> 3, i8 = (fl & 7) * 8;
      uint4 u = *(const uint4*)(BT2 + (size_t)n * 64 + i8);
      int wb = ((n * 64 + i8) * 2) ^ ((n & 7) << 4);
      *(uint4*)(Bl + wb) = u;
    }
  }
  __syncthreads();

  f32x4 acc2[5];
#pragma unroll
  for (int j = 0; j < 5; ++j) acc2[j] = (f32x4){0.f, 0.f, 0.f, 0.f};
#pragma unroll
  for (int ks = 0; ks < 2; ++ks) {
    int ra = wid * 16 + l15;
    int byte = ((ra * 64 + ks * 32 + g * 8) * 2) ^ ((ra & 7) << 4);
    bf16x8 af = *(const bf16x8*)(Al + byte);
#pragma unroll
    for (int ni = 0; ni < 5; ++ni) {
      int n = ni * 16 + l15;
      int nb = ((n * 64 + ks * 32 + g * 8) * 2) ^ ((n & 7) << 4);
      bf16x8 bfr = *(const bf16x8*)(Bl + nb);
      acc2[ni] = __builtin_amdgcn_mfma_f32_16x16x32_bf16(af, bfr, acc2[ni], 0, 0, 0);
    }
  }
  int rb = wid * 16 + 4 * g;
#pragma unroll
  for (int ni = 0; ni < 5; ++ni) {
    int n0 = ni * 16;
    int n = n0 + l15;
#pragma unroll
    for (int e = 0; e < 4; ++e) {
      int gno = bkt * 64 + rb + e;
      if (gno >= NN) continue;
      float vv = acc2[ni][e];
      if (n0 < 64) hw2[(size_t)gno * 64 + n] = f2bf(vv);
      else out[(size_t)gno * 16 + (n - 64)] = vv + L2b[n - 64];
    }
  }
}

// ---- pull-L2: copy prebuilt CSR, 2-node-interleaved gather ----
__global__ __launch_bounds__(256) void pull2_kernel(const unsigned short* __restrict__ hw2,
                                                    const int* __restrict__ binned,
                                                    const int* __restrict__ gcur,
                                                    const unsigned* __restrict__ hdrG,
                                                    const float* __restrict__ winvG,
                                                    float* __restrict__ out) {
  __shared__ int csr[BCAP];
  __shared__ float winvL[256];
  __shared__ int begL[64], totL[64];
  __shared__ float ot[64][16];
  const int t = threadIdx.x, bkt = blockIdx.x;
  const int wid = t >> 6, lane = t & 63;

  int count = gcur[bkt];
  if (count > BCAP) count = BCAP;
  for (int i = t; i < count; i += 256) csr[i] = binned[(size_t)bkt * BCAP + i];
  winvL[t] = winvG[bkt * 256 + t];
  if (t < 64) {
    unsigned hd = hdrG[bkt * 64 + t];
    begL[t] = hd & 0xffff;
    totL[t] = hd >> 16;
  }
  __syncthreads();

  const int slot = lane >> 2, cpart = lane & 3;
  for (int ii = 0; ii < 16; ii += 2) {
    int nA = wid * 16 + ii, nB = nA + 1;
    int begA = begL[nA], totA = totL[nA];
    int begB = begL[nB], totB = totL[nB];
    int tmax = totA > totB ? totA : totB;
    float accA[4] = {0.f, 0.f, 0.f, 0.f};
    float accB[4] = {0.f, 0.f, 0.f, 0.f};
    for (int p0 = 0; p0 < tmax; p0 += 16) {
      int j = p0 + slot;
      bool prA = j < totA, prB = j < totB;
      int keyA = prA ? csr[begA + j] : 0;
      int keyB = prB ? csr[begB + j] : 0;
      float wvA = prA ? winvL[nA * 4 + (keyA & 3)] : 0.f;
      float wvB = prB ? winvL[nB * 4 + (keyB & 3)] : 0.f;
      uint2 uA = *(const uint2*)(hw2 + (size_t)keyA * 16 + cpart * 4);
      uint2 uB = *(const uint2*)(hw2 + (size_t)keyB * 16 + cpart * 4);
      accA[0] = fmaf(wvA, bf2f((unsigned short)(uA.x & 0xffffu)), accA[0]);
      accA[1] = fmaf(wvA, bf2f((unsigned short)(uA.x >> 16)), accA[1]);
      accA[2] = fmaf(wvA, bf2f((unsigned short)(uA.y & 0xffffu)), accA[2]);
      accA[3] = fmaf(wvA, bf2f((unsigned short)(uA.y >> 16)), accA[3]);
      accB[0] = fmaf(wvB, bf2f((unsigned short)(uB.x & 0xffffu)), accB[0]);
      accB[1] = fmaf(wvB, bf2f((unsigned short)(uB.x >> 16)), accB[1]);
      accB[2] = fmaf(wvB, bf2f((unsigned short)(uB.y & 0xffffu)), accB[2]);
      accB[3] = fmaf(wvB, bf2f((unsigned short)(uB.y >> 16)), accB[3]);
    }
#pragma unroll
    for (int m = 4; m <= 32; m <<= 1)
#pragma unroll
      for (int q = 0; q < 4; ++q) {
        accA[q] += __shfl_xor(accA[q], m);
        accB[q] += __shfl_xor(accB[q], m);
      }
    if (slot == 0) {
      *(float4*)&ot[nA][cpart * 4] = make_float4(accA[0], accA[1], accA[2], accA[3]);
      *(float4*)&ot[nB][cpart * 4] = make_float4(accB[0], accB[1], accB[2], accB[3]);
    }
  }
  __syncthreads();

  int row = t >> 2, q = t & 3;
  int gn = bkt * 64 + row;
  if (gn < NN) {
    float4 o = *(float4*)(out + (size_t)gn * 16 + q * 4);
    float4 a = *(float4*)&ot[row][q * 4];
    o.x += a.x; o.y += a.y; o.z += a.z; o.w += a.w;
    *(float4*)(out + (size_t)gn * 16 + q * 4) = o;
  }
}

extern "C" void kernel_launch(void* const* d_in, const int* in_sizes, int n_in,
                              void* d_out, int out_size, void* d_ws, size_t ws_size,
                              hipStream_t stream) {
  const float* x   = (const float*)d_in[0];
  const int*   src = (const int*)d_in[1];
  const int*   dst = (const int*)d_in[2];
  const float* W1  = (const float*)d_in[3];
  const float* L1w = (const float*)d_in[4];
  const float* L1b = (const float*)d_in[5];
  const float* W2  = (const float*)d_in[6];
  const float* L2w = (const float*)d_in[7];
  const float* L2b = (const float*)d_in[8];
  float* out = (float*)d_out;

  char* p = (char*)d_ws;
  int* binned = (int*)p;                      p += (size_t)NBKT * BCAP * 4;      // 19.2 MB
  int* gcur   = (int*)p;                      p += 49 * 32 * 4;
  int* gcoarse = (int*)p;                     p += 64 * 4;
  int* cbuf   = (int*)p;                      p += (size_t)NCOARSE * CCAP * 4;   // 13.65 MB
  unsigned short* hwcat = (unsigned short*)p; p += (size_t)NN * 256 * 2;         // 51.2 MB
  unsigned short* h = (unsigned short*)p;     p += (size_t)NN * 64 * 2;          // 12.8 MB
  unsigned short* hw2 = (unsigned short*)p;   p += (size_t)NN * 64 * 2;          // 12.8 MB
  unsigned short* BT1 = (unsigned short*)p;   p += 320 * 256 * 2;
  unsigned short* BT2 = (unsigned short*)p;   p += 80 * 64 * 2;
  unsigned* hdrG = (unsigned*)p;              p += (size_t)NBKT * 64 * 4;        // 400 KB
  float* winvG = (float*)p;                   p += (size_t)NBKT * 256 * 4;       // 1.6 MB
  if ((size_t)(p - (char*)d_ws) > ws_size) return;  // visible fail (poison stays)

  hipMemsetAsync(gcur, 0, (49 * 32 + 64) * 4, stream);   // gcur + gcoarse
  prep_w_kernel<<<(320 * 256 + 80 * 64 + 255) / 256, 256, 0, stream>>>(W1, L1w, W2, L2w, BT1, BT2);
  fused1_kernel<<<NG1 + NB, 512, 0, stream>>>(x, BT1, L1b, src, dst, gcoarse, cbuf, hwcat, h);
  pass2_kernel<<<NCOARSE * NCH, 512, 0, stream>>>(cbuf, gcoarse, gcur, binned);
  pull1_kernel<<<NBKT, 256, 0, stream>>>(h, hwcat, binned, gcur, BT2, L2b, hdrG, winvG, hw2, out);
  pull2_kernel<<<NBKT, 256, 0, stream>>>(hw2, binned, gcur, hdrG, winvG, out);
}